// Round 1
// baseline (880.299 us; speedup 1.0000x reference)
//
#include <hip/hip_runtime.h>

#define NPROP 64

// ---------------------------------------------------------------------------
// Phase 1: per-atom-row transform.  rows = N_ATOMS * X_DIM = 150000.
//   A[r,g] = sum_z px[r,z] * wi[z,g];  B[r,g] = sum_z px[r,z] * wj[z,g]
// Block = 64 threads (one wave): lane g owns output column g, holds
// wi[:,g] and wj[:,g] in 128 VGPRs.  Row base address depends only on
// blockIdx + uniform loop counter -> compiler scalarizes px row loads
// (s_load), so the broadcast costs no DS/VALU ops.
// ---------------------------------------------------------------------------
__global__ __launch_bounds__(64, 2)
void transform_kernel(const float* __restrict__ px,
                      const float* __restrict__ wi,
                      const float* __restrict__ wj,
                      float* __restrict__ A,
                      float* __restrict__ B,
                      int nrows) {
    const int g = threadIdx.x;  // 0..63, column index

    float WA[NPROP], WB[NPROP];
#pragma unroll
    for (int z = 0; z < NPROP; ++z) {
        WA[z] = wi[z * NPROP + g];
        WB[z] = wj[z * NPROP + g];
    }

    for (int r = blockIdx.x; r < nrows; r += gridDim.x) {
        const float* __restrict__ row = px + (size_t)r * NPROP;
        float a = 0.0f, b = 0.0f;
#pragma unroll
        for (int z = 0; z < NPROP; ++z) {
            float v = row[z];  // wave-uniform -> scalar load
            a = fmaf(v, WA[z], a);
            b = fmaf(v, WB[z], b);
        }
        A[(size_t)r * NPROP + g] = a;  // coalesced 256B store
        B[(size_t)r * NPROP + g] = b;
    }
}

// ---------------------------------------------------------------------------
// Phase 2: gather + add, float4-vectorized.  48 float4 per pair (3*64 floats).
//   out4[p*48 + r] = A4[i_p*48 + r] + B4[j_p*48 + r]
// ---------------------------------------------------------------------------
__global__ __launch_bounds__(256)
void gather_add_kernel(const int* __restrict__ ind,
                       const float4* __restrict__ A,
                       const float4* __restrict__ B,
                       float4* __restrict__ out,
                       int total_f4) {
    int f = blockIdx.x * 256 + threadIdx.x;
    if (f >= total_f4) return;
    unsigned uf = (unsigned)f;
    unsigned pair = uf / 48u;          // magic-mul, no HW divide
    unsigned r = uf - pair * 48u;
    int i = ind[2u * pair];
    int j = ind[2u * pair + 1u];
    float4 a = A[(size_t)i * 48u + r];
    float4 b = B[(size_t)j * 48u + r];
    float4 o;
    o.x = a.x + b.x;
    o.y = a.y + b.y;
    o.z = a.z + b.z;
    o.w = a.w + b.w;
    out[f] = o;
}

// ---------------------------------------------------------------------------
// Fallback (only if ws_size < 76.8 MB): fused direct computation, correct
// but slow.  wi/wj staged in LDS; one wave per (pair,x) row.
// ---------------------------------------------------------------------------
__global__ __launch_bounds__(256)
void naive_fused_kernel(const int* __restrict__ ind,
                        const float* __restrict__ px,
                        const float* __restrict__ wi,
                        const float* __restrict__ wj,
                        float* __restrict__ out,
                        int npairs) {
    __shared__ float swi[NPROP * NPROP];
    __shared__ float swj[NPROP * NPROP];
    for (int t = threadIdx.x; t < NPROP * NPROP; t += 256) {
        swi[t] = wi[t];
        swj[t] = wj[t];
    }
    __syncthreads();

    const int lane = threadIdx.x & 63;
    const int w = threadIdx.x >> 6;
    const long nrows = (long)npairs * 3;
    for (long row = (long)blockIdx.x * 4 + w; row < nrows;
         row += (long)gridDim.x * 4) {
        int p = (int)(row / 3);
        int x = (int)(row - (long)p * 3);
        int i = ind[2 * p];
        int j = ind[2 * p + 1];
        const float* ri = px + ((size_t)i * 3 + x) * NPROP;
        const float* rj = px + ((size_t)j * 3 + x) * NPROP;
        float acc = 0.0f;
        for (int z = 0; z < NPROP; ++z) {
            acc = fmaf(ri[z], swi[z * NPROP + lane],
                       fmaf(rj[z], swj[z * NPROP + lane], acc));
        }
        out[row * NPROP + lane] = acc;
    }
}

extern "C" void kernel_launch(void* const* d_in, const int* in_sizes, int n_in,
                              void* d_out, int out_size, void* d_ws, size_t ws_size,
                              hipStream_t stream) {
    const int* ind = (const int*)d_in[0];     // (NPAIRS, 2) int32
    const float* px = (const float*)d_in[1];  // (NATOMS, 3, 64) fp32
    const float* wi = (const float*)d_in[2];  // (64, 64) fp32
    const float* wj = (const float*)d_in[3];  // (64, 64) fp32
    float* out = (float*)d_out;               // (NPAIRS, 3, 64) fp32

    const int npairs = in_sizes[0] / 2;
    const int nrows = in_sizes[1] / NPROP;    // NATOMS * 3

    const size_t need = 2 * (size_t)nrows * NPROP * sizeof(float);
    if (ws_size >= need) {
        float* A = (float*)d_ws;
        float* B = A + (size_t)nrows * NPROP;
        // Phase 1: 4096 blocks x 1 wave, each loops ~37 rows (weight-load
        // amortized ~37x).
        transform_kernel<<<4096, 64, 0, stream>>>(px, wi, wj, A, B, nrows);
        // Phase 2: one thread per output float4.
        int total_f4 = npairs * 48;
        gather_add_kernel<<<(total_f4 + 255) / 256, 256, 0, stream>>>(
            ind, (const float4*)A, (const float4*)B, (float4*)out, total_f4);
    } else {
        naive_fused_kernel<<<8192, 256, 0, stream>>>(ind, px, wi, wj, out,
                                                     npairs);
    }
}